// Round 1
// baseline (206.456 us; speedup 1.0000x reference)
//
#include <hip/hip_runtime.h>

#define BB 8
#define LL 512
#define KK 512
#define DD 64
#define TL 4   // l-rows per block in the attention kernel

// ---------------------------------------------------------------------------
// Kernel A: vkc[b,k,n] = sum_p vk[b,k,p,n] * vexp[b,k,p]
// One wave per (b,k) row. Fully coalesced: each wave-instr reads 4 consecutive
// p-rows (1 KB contiguous). P-split reduced with shuffles.
// ---------------------------------------------------------------------------
__global__ __launch_bounds__(256) void vkc_kernel(const float* __restrict__ vk,
                                                  const float* __restrict__ vexp,
                                                  float* __restrict__ vkc) {
    const int wave = (blockIdx.x << 2) + (threadIdx.x >> 6);  // 0..4095 = b*K+k
    const int lane = threadIdx.x & 63;

    const float ve_reg = vexp[wave * 64 + lane];   // lane l holds vexp[p=l]
    const int n0 = (lane & 15) << 2;
    const float* base = vk + (long)wave * (64 * 64);

    float ax = 0.f, ay = 0.f, az = 0.f, aw = 0.f;
    #pragma unroll
    for (int it = 0; it < 16; ++it) {
        const int p = (lane >> 4) + (it << 2);
        const float4 v4 = *(const float4*)(base + p * 64 + n0);
        const float w = __shfl(ve_reg, p, 64);
        ax += v4.x * w; ay += v4.y * w; az += v4.z * w; aw += v4.w * w;
    }
    // reduce over the 4 p-groups (lanes l, l+16, l+32, l+48)
    ax += __shfl_down(ax, 32, 64); ax += __shfl_down(ax, 16, 64);
    ay += __shfl_down(ay, 32, 64); ay += __shfl_down(ay, 16, 64);
    az += __shfl_down(az, 32, 64); az += __shfl_down(az, 16, 64);
    aw += __shfl_down(aw, 32, 64); aw += __shfl_down(aw, 16, 64);

    if ((lane & 48) == 0) {  // lanes 0..15
        float4 r; r.x = ax; r.y = ay; r.z = az; r.w = aw;
        *(float4*)(vkc + wave * 64 + n0) = r;
    }
}

// ---------------------------------------------------------------------------
// Kernel B: per-(batch, 4 l-rows) fused attention:
//   scores -> softmax -> tmp = weights @ vkc -> attn = vq @ tmp -> res + LN
// ---------------------------------------------------------------------------
__global__ __launch_bounds__(256) void attn_kernel(const float* __restrict__ q,
                                                   const float* __restrict__ k,
                                                   const float* __restrict__ vq,
                                                   const float* __restrict__ vkc,
                                                   const float* __restrict__ scale_p,
                                                   const float* __restrict__ gamma,
                                                   const float* __restrict__ beta,
                                                   float* __restrict__ out) {
    __shared__ float q_s[TL * 64];        // 4 q rows
    __shared__ float sc[TL][KK];          // scores -> weights (in place)
    __shared__ float tmpp[4][TL][64];     // per-wave partial tmp
    __shared__ float tmp_s[TL][64];       // reduced tmp
    __shared__ float attn_s[TL][64];      // attn output per l

    const int t = threadIdx.x;
    const int wave = t >> 6;
    const int lane = t & 63;
    const int blk = blockIdx.x;          // 0..1023
    const int batch = blk >> 7;          // 128 blocks per batch
    const int l0 = (blk & 127) * TL;

    const float scale = scale_p[0];

    // ---- phase 0: stage q rows (256 consecutive floats, coalesced) ----
    q_s[t] = q[(batch * LL + l0) * 64 + t];
    __syncthreads();

    // ---- phase 1: scores[l][kk] = scale * dot(q[l], k[kk]) ----
    {
        const float* kb = k + batch * KK * 64;
        const float4* q4 = (const float4*)q_s;
        #pragma unroll
        for (int it = 0; it < 2; ++it) {
            const int kk = t + it * 256;
            const float4* krow = (const float4*)(kb + kk * 64);
            float a0 = 0.f, a1 = 0.f, a2 = 0.f, a3 = 0.f;
            #pragma unroll
            for (int dc = 0; dc < 16; ++dc) {
                const float4 kv = krow[dc];
                const float4 p0 = q4[0 * 16 + dc];
                const float4 p1 = q4[1 * 16 + dc];
                const float4 p2 = q4[2 * 16 + dc];
                const float4 p3 = q4[3 * 16 + dc];
                a0 += p0.x * kv.x + p0.y * kv.y + p0.z * kv.z + p0.w * kv.w;
                a1 += p1.x * kv.x + p1.y * kv.y + p1.z * kv.z + p1.w * kv.w;
                a2 += p2.x * kv.x + p2.y * kv.y + p2.z * kv.z + p2.w * kv.w;
                a3 += p3.x * kv.x + p3.y * kv.y + p3.z * kv.z + p3.w * kv.w;
            }
            sc[0][kk] = scale * a0;
            sc[1][kk] = scale * a1;
            sc[2][kk] = scale * a2;
            sc[3][kk] = scale * a3;
        }
    }
    __syncthreads();

    // ---- phase 2: softmax over K for l = wave ----
    {
        float v[8];
        float mx = -1e30f;
        #pragma unroll
        for (int j = 0; j < 8; ++j) {
            v[j] = sc[wave][lane + 64 * j];
            mx = fmaxf(mx, v[j]);
        }
        #pragma unroll
        for (int off = 32; off; off >>= 1) mx = fmaxf(mx, __shfl_xor(mx, off, 64));
        float s = 0.f;
        #pragma unroll
        for (int j = 0; j < 8; ++j) { v[j] = __expf(v[j] - mx); s += v[j]; }
        #pragma unroll
        for (int off = 32; off; off >>= 1) s += __shfl_xor(s, off, 64);
        const float inv = 1.0f / s;
        #pragma unroll
        for (int j = 0; j < 8; ++j) sc[wave][lane + 64 * j] = v[j] * inv;
    }
    __syncthreads();

    // ---- phase 3: tmp[l][n] = sum_k w[l][k] * vkc[b][k][n] (k-split by wave) ----
    {
        const float* vkcb = vkc + batch * KK * 64;
        float a0 = 0.f, a1 = 0.f, a2 = 0.f, a3 = 0.f;
        const int kbeg = wave * 128;
        for (int kk = kbeg; kk < kbeg + 128; ++kk) {
            const float vv = vkcb[kk * 64 + lane];   // coalesced 256B
            a0 += sc[0][kk] * vv;                    // broadcast LDS reads
            a1 += sc[1][kk] * vv;
            a2 += sc[2][kk] * vv;
            a3 += sc[3][kk] * vv;
        }
        tmpp[wave][0][lane] = a0;
        tmpp[wave][1][lane] = a1;
        tmpp[wave][2][lane] = a2;
        tmpp[wave][3][lane] = a3;
    }
    __syncthreads();
    {   // reduce the 4 wave partials; t = l*64 + n
        tmp_s[wave][lane] = tmpp[0][wave][lane] + tmpp[1][wave][lane] +
                            tmpp[2][wave][lane] + tmpp[3][wave][lane];
    }
    __syncthreads();

    // ---- phase 4: attn[l][m] = sum_n vq[b,l,m,n] * tmp[l][n]; l = wave ----
    {
        const float* vql = vq + (long)(batch * LL + l0 + wave) * 4096;
        const int n0 = (lane & 15) << 2;
        const float4 t4 = *(const float4*)&tmp_s[wave][n0];
        #pragma unroll
        for (int it = 0; it < 16; ++it) {
            const int flat = it * 256 + lane * 4;    // fully coalesced 1KB/instr
            const float4 v4 = *(const float4*)(vql + flat);
            float part = v4.x * t4.x + v4.y * t4.y + v4.z * t4.z + v4.w * t4.w;
            // sum over the 16 lanes sharing m = it*4 + (lane>>4)
            part += __shfl_down(part, 8, 16);
            part += __shfl_down(part, 4, 16);
            part += __shfl_down(part, 2, 16);
            part += __shfl_down(part, 1, 16);
            if ((lane & 15) == 0) attn_s[wave][it * 4 + (lane >> 4)] = part;
        }
    }
    // attn_s[wave] written and read by the same wave -> no block barrier needed

    // ---- phase 5: residual + LayerNorm over D=64; l = wave, lane = m ----
    {
        const float x = q_s[wave * 64 + lane] + attn_s[wave][lane];
        float s1 = x, s2 = x * x;
        #pragma unroll
        for (int off = 32; off; off >>= 1) {
            s1 += __shfl_xor(s1, off, 64);
            s2 += __shfl_xor(s2, off, 64);
        }
        const float mean = s1 * (1.0f / 64.0f);
        const float var = s2 * (1.0f / 64.0f) - mean * mean;
        const float r = rsqrtf(var + 1e-3f);
        const float y = (x - mean) * r * gamma[lane] + beta[lane];
        out[(batch * LL + l0 + wave) * 64 + lane] = y;
    }
}

extern "C" void kernel_launch(void* const* d_in, const int* in_sizes, int n_in,
                              void* d_out, int out_size, void* d_ws, size_t ws_size,
                              hipStream_t stream) {
    const float* q     = (const float*)d_in[0];
    const float* k     = (const float*)d_in[1];
    const float* vq    = (const float*)d_in[2];
    const float* vk    = (const float*)d_in[3];
    const float* vexp  = (const float*)d_in[4];
    const float* scale = (const float*)d_in[5];
    const float* gamma = (const float*)d_in[6];
    const float* beta  = (const float*)d_in[7];
    float* out = (float*)d_out;
    float* vkc = (float*)d_ws;   // B*K*N fp32 = 1 MB

    vkc_kernel<<<1024, 256, 0, stream>>>(vk, vexp, vkc);
    attn_kernel<<<1024, 256, 0, stream>>>(q, k, vq, vkc, scale, gamma, beta, out);
}